// Round 1
// baseline (177.972 us; speedup 1.0000x reference)
//
#include <hip/hip_runtime.h>

// LRFGraphConv: out[v] = ((sum_{t in N(v)} (verts[t]-verts[v])) @ lrf[v]) @ W^T + maxN*b
// Exploits linearity: reduce the 3-vector per vertex FIRST, then do the dense
// 3x3 rotate + 3->128 projection once per vertex.

__global__ __launch_bounds__(256)
void lrf_accum(const float* __restrict__ verts,
               const int* __restrict__ edges,
               float* __restrict__ nbr,
               int* __restrict__ deg,
               int E) {
    int i = blockIdx.x * blockDim.x + threadIdx.x;
    if (i >= E) return;
    int a = edges[2 * i + 0];
    int b = edges[2 * i + 1];
    float ax = verts[3 * a + 0], ay = verts[3 * a + 1], az = verts[3 * a + 2];
    float bx = verts[3 * b + 0], by = verts[3 * b + 1], bz = verts[3 * b + 2];
    // center a gets neighbor b's coords, and vice versa
    atomicAdd(&nbr[3 * a + 0], bx);
    atomicAdd(&nbr[3 * a + 1], by);
    atomicAdd(&nbr[3 * a + 2], bz);
    atomicAdd(&nbr[3 * b + 0], ax);
    atomicAdd(&nbr[3 * b + 1], ay);
    atomicAdd(&nbr[3 * b + 2], az);
    atomicAdd(&deg[a], 1);
    atomicAdd(&deg[b], 1);
}

__global__ __launch_bounds__(256)
void lrf_maxdeg(const int* __restrict__ deg, int* __restrict__ maxN, int V) {
    int i = blockIdx.x * blockDim.x + threadIdx.x;
    int stride = gridDim.x * blockDim.x;
    int m = 0;
    for (; i < V; i += stride) m = max(m, deg[i]);
    // wave-64 reduction, then one atomic per wave
    #pragma unroll
    for (int off = 32; off > 0; off >>= 1)
        m = max(m, __shfl_down(m, off, 64));
    if ((threadIdx.x & 63) == 0) atomicMax(maxN, m);
}

__global__ __launch_bounds__(256)
void lrf_out(const float* __restrict__ verts,
             const float* __restrict__ lrf,
             const float* __restrict__ W,
             const float* __restrict__ bias,
             const float* __restrict__ nbr,
             const int* __restrict__ deg,
             const int* __restrict__ maxN,
             float* __restrict__ out,
             int V) {
    // 256 threads / block, 2 vertices / block, D_OUT = 128
    int v = blockIdx.x * 2 + (threadIdx.x >> 7);
    int d = threadIdx.x & 127;
    if (v >= V) return;

    float degf = (float)deg[v];
    float mx = (float)maxN[0];

    float s0 = nbr[3 * v + 0] - degf * verts[3 * v + 0];
    float s1 = nbr[3 * v + 1] - degf * verts[3 * v + 1];
    float s2 = nbr[3 * v + 2] - degf * verts[3 * v + 2];

    const float* L = lrf + (size_t)9 * v;  // lrf[v, j, k] row-major
    float r0 = s0 * L[0] + s1 * L[3] + s2 * L[6];
    float r1 = s0 * L[1] + s1 * L[4] + s2 * L[7];
    float r2 = s0 * L[2] + s1 * L[5] + s2 * L[8];

    float w0 = W[3 * d + 0], w1 = W[3 * d + 1], w2 = W[3 * d + 2];
    out[(size_t)v * 128 + d] = r0 * w0 + r1 * w1 + r2 * w2 + mx * bias[d];
}

extern "C" void kernel_launch(void* const* d_in, const int* in_sizes, int n_in,
                              void* d_out, int out_size, void* d_ws, size_t ws_size,
                              hipStream_t stream) {
    const float* verts = (const float*)d_in[0];
    const int*   edges = (const int*)d_in[1];
    const float* lrf   = (const float*)d_in[2];
    const float* W     = (const float*)d_in[3];
    const float* bias  = (const float*)d_in[4];
    float* out = (float*)d_out;

    int V = in_sizes[0] / 3;
    int E = in_sizes[1] / 2;

    // workspace layout: [deg: V ints][maxN: 1 int][pad][nbr: 3V floats]
    int* deg = (int*)d_ws;
    int* maxN = deg + V;
    int nInts = ((V + 1 + 15) / 16) * 16;            // 16-int alignment for nbr
    float* nbr = (float*)((char*)d_ws + (size_t)nInts * 4);
    size_t zero_bytes = (size_t)nInts * 4 + (size_t)V * 3 * 4;

    hipMemsetAsync(d_ws, 0, zero_bytes, stream);

    int blocks1 = (E + 255) / 256;
    lrf_accum<<<blocks1, 256, 0, stream>>>(verts, edges, nbr, deg, E);

    lrf_maxdeg<<<128, 256, 0, stream>>>(deg, maxN, V);

    int blocks3 = (V + 1) / 2;
    lrf_out<<<blocks3, 256, 0, stream>>>(verts, lrf, W, bias, nbr, deg, maxN, out, V);
}

// Round 2
// 82.407 us; speedup vs baseline: 2.1597x; 2.1597x over previous
//
#include <hip/hip_runtime.h>

// LRFGraphConv: out[v] = ((sum_{t in N(v)} (verts[t]-verts[v])) @ lrf[v]) @ W^T + maxN*b
// = ((nbr_sum[v] - deg[v]*verts[v]) @ lrf[v]) @ W^T + maxN*b
//
// R2 design: NO global atomics (they are near-memory RMW on MI355X -> 91MB HBM
// write traffic in R1). Instead: grid of (NS edge-slices x NB vertex-ranges);
// each block scans its edge slice, accumulates its vertex range in LDS
// (workgroup-scope LDS atomics), flushes to per-slice partials (in d_out used
// as scratch), then a reduce pass sums partials, then the projection pass
// fully rewrites d_out.

#define NS  16     // edge slices
#define VPB 1024   // vertices per range-block (LDS: 4 arrays x 1024 x 4B = 16KB)

__global__ __launch_bounds__(256)
void scan_accum(const float* __restrict__ verts,
                const int*   __restrict__ edges,
                float4* __restrict__ partial,   // [NS][V] (sumx,sumy,sumz,deg)
                int V, int E, int NB) {
    __shared__ float accx[VPB], accy[VPB], accz[VPB], accd[VPB];
    int r = blockIdx.x % NB;   // vertex range
    int s = blockIdx.x / NB;   // edge slice
    int v0 = r * VPB;
    int v1 = min(v0 + VPB, V);
    int nv = v1 - v0;
    for (int i = threadIdx.x; i < nv; i += blockDim.x) {
        accx[i] = 0.f; accy[i] = 0.f; accz[i] = 0.f; accd[i] = 0.f;
    }
    __syncthreads();

    int npairs = E >> 1;
    int p0 = (int)(((long long)npairs * s) / NS);
    int p1 = (int)(((long long)npairs * (s + 1)) / NS);
    const int4* e4 = (const int4*)edges;

    for (int p = p0 + threadIdx.x; p < p1; p += blockDim.x) {
        int4 e = e4[p];   // edges (e.x,e.y) and (e.z,e.w)
        if (e.x >= v0 && e.x < v1) {   // center e.x gets neighbor e.y
            int li = e.x - v0;
            atomicAdd(&accx[li], verts[3 * e.y + 0]);
            atomicAdd(&accy[li], verts[3 * e.y + 1]);
            atomicAdd(&accz[li], verts[3 * e.y + 2]);
            atomicAdd(&accd[li], 1.f);
        }
        if (e.y >= v0 && e.y < v1) {
            int li = e.y - v0;
            atomicAdd(&accx[li], verts[3 * e.x + 0]);
            atomicAdd(&accy[li], verts[3 * e.x + 1]);
            atomicAdd(&accz[li], verts[3 * e.x + 2]);
            atomicAdd(&accd[li], 1.f);
        }
        if (e.z >= v0 && e.z < v1) {
            int li = e.z - v0;
            atomicAdd(&accx[li], verts[3 * e.w + 0]);
            atomicAdd(&accy[li], verts[3 * e.w + 1]);
            atomicAdd(&accz[li], verts[3 * e.w + 2]);
            atomicAdd(&accd[li], 1.f);
        }
        if (e.w >= v0 && e.w < v1) {
            int li = e.w - v0;
            atomicAdd(&accx[li], verts[3 * e.z + 0]);
            atomicAdd(&accy[li], verts[3 * e.z + 1]);
            atomicAdd(&accz[li], verts[3 * e.z + 2]);
            atomicAdd(&accd[li], 1.f);
        }
    }
    // odd trailing edge (E odd): handled once per range by slice NS-1
    if ((E & 1) && s == NS - 1 && threadIdx.x == 0) {
        int a = edges[2 * (E - 1) + 0];
        int b = edges[2 * (E - 1) + 1];
        if (a >= v0 && a < v1) {
            int li = a - v0;
            atomicAdd(&accx[li], verts[3 * b + 0]);
            atomicAdd(&accy[li], verts[3 * b + 1]);
            atomicAdd(&accz[li], verts[3 * b + 2]);
            atomicAdd(&accd[li], 1.f);
        }
        if (b >= v0 && b < v1) {
            int li = b - v0;
            atomicAdd(&accx[li], verts[3 * a + 0]);
            atomicAdd(&accy[li], verts[3 * a + 1]);
            atomicAdd(&accz[li], verts[3 * a + 2]);
            atomicAdd(&accd[li], 1.f);
        }
    }
    __syncthreads();

    float4* dst = partial + (size_t)s * V + v0;
    for (int i = threadIdx.x; i < nv; i += blockDim.x)
        dst[i] = make_float4(accx[i], accy[i], accz[i], accd[i]);
}

__global__ __launch_bounds__(256)
void reduce_nbr(const float4* __restrict__ partial,
                float4* __restrict__ nbrdeg,
                int* __restrict__ maxN, int V) {
    int v = blockIdx.x * blockDim.x + threadIdx.x;
    float4 acc = make_float4(0.f, 0.f, 0.f, 0.f);
    if (v < V) {
        #pragma unroll
        for (int s = 0; s < NS; ++s) {
            float4 p = partial[(size_t)s * V + v];
            acc.x += p.x; acc.y += p.y; acc.z += p.z; acc.w += p.w;
        }
        nbrdeg[v] = acc;
    }
    int m = (int)acc.w;
    #pragma unroll
    for (int off = 32; off > 0; off >>= 1)
        m = max(m, __shfl_down(m, off, 64));
    if ((threadIdx.x & 63) == 0) atomicMax(maxN, m);
}

__global__ __launch_bounds__(256)
void lrf_out(const float* __restrict__ verts,
             const float* __restrict__ lrf,
             const float4* __restrict__ W4,     // W as float4[96]
             const float4* __restrict__ bias4,  // bias as float4[32]
             const float4* __restrict__ nbrdeg,
             const int* __restrict__ maxN,
             float4* __restrict__ out4,         // out as float4[V*32]
             int V) {
    int t = blockIdx.x * blockDim.x + threadIdx.x;
    int v = t >> 5;        // vertex
    int q = t & 31;        // output quad: dims 4q..4q+3
    if (v >= V) return;

    float4 nd = nbrdeg[v];
    float s0 = nd.x - nd.w * verts[3 * v + 0];
    float s1 = nd.y - nd.w * verts[3 * v + 1];
    float s2 = nd.z - nd.w * verts[3 * v + 2];

    const float* L = lrf + (size_t)9 * v;   // lrf[v,j,k] row-major
    float r0 = s0 * L[0] + s1 * L[3] + s2 * L[6];
    float r1 = s0 * L[1] + s1 * L[4] + s2 * L[7];
    float r2 = s0 * L[2] + s1 * L[5] + s2 * L[8];

    // W rows 4q..4q+3 are floats [12q .. 12q+11] = float4 {3q, 3q+1, 3q+2}
    float4 w0 = W4[3 * q + 0];
    float4 w1 = W4[3 * q + 1];
    float4 w2 = W4[3 * q + 2];
    float mx = (float)maxN[0];
    float4 bv = bias4[q];

    float4 o;
    o.x = r0 * w0.x + r1 * w0.y + r2 * w0.z + mx * bv.x;
    o.y = r0 * w0.w + r1 * w1.x + r2 * w1.y + mx * bv.y;
    o.z = r0 * w1.z + r1 * w1.w + r2 * w2.x + mx * bv.z;
    o.w = r0 * w2.y + r1 * w2.z + r2 * w2.w + mx * bv.w;
    out4[(size_t)v * 32 + q] = o;
}

extern "C" void kernel_launch(void* const* d_in, const int* in_sizes, int n_in,
                              void* d_out, int out_size, void* d_ws, size_t ws_size,
                              hipStream_t stream) {
    const float* verts = (const float*)d_in[0];
    const int*   edges = (const int*)d_in[1];
    const float* lrf   = (const float*)d_in[2];
    const float* W     = (const float*)d_in[3];
    const float* bias  = (const float*)d_in[4];

    int V = in_sizes[0] / 3;
    int E = in_sizes[1] / 2;
    int NB = (V + VPB - 1) / VPB;

    // ws layout: [maxN int][pad to 16B][nbrdeg: V float4]
    int* maxN = (int*)d_ws;
    float4* nbrdeg = (float4*)((char*)d_ws + 16);

    // per-slice partials live in d_out (fully overwritten by lrf_out at the end)
    float4* partial = (float4*)d_out;

    hipMemsetAsync(maxN, 0, 4, stream);

    scan_accum<<<NS * NB, 256, 0, stream>>>(verts, edges, partial, V, E, NB);

    int rb = (V + 255) / 256;
    reduce_nbr<<<rb, 256, 0, stream>>>(partial, nbrdeg, maxN, V);

    int ob = (V * 32 + 255) / 256;
    lrf_out<<<ob, 256, 0, stream>>>(verts, lrf, (const float4*)W,
                                    (const float4*)bias, nbrdeg, maxN,
                                    (float4*)d_out, V);
}